// Round 17
// baseline (1178.713 us; speedup 1.0000x reference)
//
#include <hip/hip_runtime.h>
#include <hip/hip_bf16.h>

using f32x4 = __attribute__((ext_vector_type(4))) float;
using s16x8 = __attribute__((ext_vector_type(8))) short;

#define MFMA __builtin_amdgcn_mfma_f32_16x16x32_bf16

__device__ __forceinline__ ushort f2b(float f) {
  union { float f; unsigned u; } v; v.f = f;
  unsigned r = v.u + 0x7fff + ((v.u >> 16) & 1);
  return (ushort)(r >> 16);
}
__device__ __forceinline__ float b2f(ushort u) {
  union { unsigned u; float f; } v; v.u = ((unsigned)u) << 16;
  return v.f;
}

__device__ __forceinline__ void load_lds16(const ushort* g, ushort* l) {
  __builtin_amdgcn_global_load_lds((const __attribute__((address_space(1))) unsigned int*)g,
                                   (__attribute__((address_space(3))) unsigned int*)l,
                                   16, 0, 0);
}

// ---------------- fused cast f32 -> bf16 for all 6 tensors ----------------
__device__ __forceinline__ void cast_seg(const float* __restrict__ in, ushort* __restrict__ out,
                                         int n8, int tid, int stride) {
  const float4* i4 = (const float4*)in;
  for (int i = tid; i < n8; i += stride) {
    float4 a = i4[i * 2];
    float4 b = i4[i * 2 + 1];
    s16x8 o;
    o[0] = f2b(a.x); o[1] = f2b(a.y); o[2] = f2b(a.z); o[3] = f2b(a.w);
    o[4] = f2b(b.x); o[5] = f2b(b.y); o[6] = f2b(b.z); o[7] = f2b(b.w);
    *(s16x8*)(out + (size_t)i * 8) = o;
  }
}

__global__ void cast6_kernel(const float* a0, ushort* b0, int n0,
                             const float* a1, ushort* b1, int n1,
                             const float* a2, ushort* b2, int n2,
                             const float* a3, ushort* b3, int n3,
                             const float* a4, ushort* b4, int n4,
                             const float* a5, ushort* b5, int n5) {
  int tid = blockIdx.x * blockDim.x + threadIdx.x;
  int stride = gridDim.x * blockDim.x;
  cast_seg(a0, b0, n0, tid, stride);
  cast_seg(a1, b1, n1, tid, stride);
  cast_seg(a2, b2, n2, tid, stride);
  cast_seg(a3, b3, n3, tid, stride);
  cast_seg(a4, b4, n4, tid, stride);
  cast_seg(a5, b5, n5, tid, stride);
}

// ---------------- rope tables: cos/sin per (b,s) row ----------------
__global__ void rope_table_kernel(const int* __restrict__ pos,
                                  float* __restrict__ cosb, float* __restrict__ sinb) {
  int i = blockIdx.x * 256 + threadIdx.x;  // 2048*64
  int d = i & 63;
  float invf = exp2f(-(float)d * (13.287712379549449f / 64.0f));  // 10000^(-d/64)
  float ang = (float)pos[i >> 6] * invf;
  cosb[i] = cosf(ang);
  sinb[i] = sinf(ang);
}

// ---------------- layernorm over 256 cols with 8-way split-K reduction ----------------
__global__ void ln_kernel(const float* __restrict__ X, const float* __restrict__ gamma,
                          const float* __restrict__ beta, ushort* __restrict__ out) {
  int row = blockIdx.x * 4 + (threadIdx.x >> 6);
  int lane = threadIdx.x & 63;
  float4 x = {0.f, 0.f, 0.f, 0.f};
#pragma unroll
  for (int sp = 0; sp < 8; ++sp) {
    const float4 t = *(const float4*)(X + (size_t)sp * 2048 * 256 + (size_t)row * 256 + lane * 4);
    x.x += t.x; x.y += t.y; x.z += t.z; x.w += t.w;
  }
  float s = x.x + x.y + x.z + x.w;
  for (int m = 32; m >= 1; m >>= 1) s += __shfl_xor(s, m);
  float mu = s * (1.0f / 256.0f);
  float dx = x.x - mu, dy = x.y - mu, dz = x.z - mu, dw = x.w - mu;
  float v = dx * dx + dy * dy + dz * dz + dw * dw;
  for (int m = 32; m >= 1; m >>= 1) v += __shfl_xor(v, m);
  float inv = rsqrtf(v * (1.0f / 256.0f) + 1e-5f);
  const float4 g = *(const float4*)(gamma + lane * 4);
  const float4 bt = *(const float4*)(beta + lane * 4);
  ushort4 o;
  o.x = f2b(dx * inv * g.x + bt.x);
  o.y = f2b(dy * inv * g.y + bt.y);
  o.z = f2b(dz * inv * g.z + bt.z);
  o.w = f2b(dw * inv * g.w + bt.w);
  *(ushort4*)(out + (size_t)row * 256 + lane * 4) = o;
}

// ---------------- rope apply in-place on bf16 [2048, NH*128] ----------------
template<int NH>
__global__ void rope_apply_bf16(ushort* __restrict__ X, const float* __restrict__ cosb,
                                const float* __restrict__ sinb) {
  int bs = blockIdx.x;
  ushort* xr = X + (size_t)bs * (NH * 128);
  int p = threadIdx.x;
  if (p < NH * 8) {
    int h = p >> 3, c8 = p & 7;
    int idx = h * 128 + c8 * 8;
    s16x8 x1 = *(s16x8*)(xr + idx);
    s16x8 x2 = *(s16x8*)(xr + idx + 64);
    const float* cb = cosb + (bs << 6) + c8 * 8;
    const float* sb = sinb + (bs << 6) + c8 * 8;
    s16x8 o1, o2;
#pragma unroll
    for (int j = 0; j < 8; ++j) {
      float a = b2f((ushort)x1[j]), bb = b2f((ushort)x2[j]);
      float c = cb[j], s = sb[j];
      o1[j] = f2b(a * c - bb * s);
      o2[j] = f2b(bb * c + a * s);
    }
    *(s16x8*)(xr + idx) = o1;
    *(s16x8*)(xr + idx + 64) = o2;
  }
}

// ---------------- O split-K reduce: out = p0 + p1 (bf16 partials -> f32) ----------------
__global__ void ored_kernel(const ushort* __restrict__ P, float* __restrict__ out, int n8) {
  int stride = gridDim.x * blockDim.x;
  for (int i = blockIdx.x * blockDim.x + threadIdx.x; i < n8; i += stride) {
    s16x8 a = *(const s16x8*)(P + (size_t)i * 8);
    s16x8 b = *(const s16x8*)(P + 2048ull * 4096 + (size_t)i * 8);
    float4 o0, o1;
    o0.x = b2f((ushort)a[0]) + b2f((ushort)b[0]);
    o0.y = b2f((ushort)a[1]) + b2f((ushort)b[1]);
    o0.z = b2f((ushort)a[2]) + b2f((ushort)b[2]);
    o0.w = b2f((ushort)a[3]) + b2f((ushort)b[3]);
    o1.x = b2f((ushort)a[4]) + b2f((ushort)b[4]);
    o1.y = b2f((ushort)a[5]) + b2f((ushort)b[5]);
    o1.z = b2f((ushort)a[6]) + b2f((ushort)b[6]);
    o1.w = b2f((ushort)a[7]) + b2f((ushort)b[7]);
    ((float4*)out)[i * 2] = o0;
    ((float4*)out)[i * 2 + 1] = o1;
  }
}

// ---------------- pipelined GEMM: C[M,N] = A[M,K]*B[N,K]^T ----------------
// 256 threads = 4 waves (2M x 2N), tile 128(M) x 256(N), BK=32; per-wave 64x128.
// DOUBLE-buffered LDS (48KB -> 3 blocks/CU = 3 waves/SIMD for latency hiding);
// stage(t+1) issued at top (loads fly across the compute phase), vmcnt(0)+raw
// s_barrier at bottom. Both-sides chunk-XOR swizzle ^((r>>1)&3): 0 conflicts.
template<bool BF16_OUT>
__global__ __launch_bounds__(256, 3)
void gemm2_bt(const ushort* __restrict__ A, int lda, const ushort* __restrict__ B, int ldb,
              void* __restrict__ Cv, int M, int N, int Kloop) {
  __shared__ ushort lA[2][128 * 32];
  __shared__ ushort lB[2][256 * 32];
  const int gx = gridDim.x;
  const int nwg = gx * gridDim.y;
  const int bid = blockIdx.y * gx + blockIdx.x;
  const int cpx = nwg >> 3;
  const int swz = (bid & 7) * cpx + (bid >> 3);
  const int bm = (swz / gx) * 128;
  const int bn = (swz % gx) * 256;
  const int lane = threadIdx.x & 63;
  const int w = threadIdx.x >> 6;
  const int wm = w >> 1, wn = w & 1;
  const int l15 = lane & 15, l4 = lane >> 4;
  const int lr = lane >> 2;
  const int lc = lane & 3;

  f32x4 acc[4][8] = {};

  const ushort* Abase = A + (size_t)blockIdx.z * Kloop;
  const ushort* Bbase = B + (size_t)blockIdx.z * Kloop;

  auto stage = [&](int bb, int k0) {
#pragma unroll
    for (int p = 0; p < 2; ++p) {
      int row0 = w * 32 + p * 16;
      int r = row0 + lr;
      const ushort* src = Abase + (size_t)(bm + r) * lda + k0 + (lc ^ ((r >> 1) & 3)) * 8;
      load_lds16(src, &lA[bb][row0 * 32]);
    }
#pragma unroll
    for (int p = 0; p < 4; ++p) {
      int row0 = w * 64 + p * 16;
      int r = row0 + lr;
      const ushort* src = Bbase + (size_t)(bn + r) * ldb + k0 + (lc ^ ((r >> 1) & 3)) * 8;
      load_lds16(src, &lB[bb][row0 * 32]);
    }
  };

  const int nt = Kloop / 32;
  stage(0, 0);
  asm volatile("s_waitcnt vmcnt(0)" ::: "memory");
  __builtin_amdgcn_s_barrier();

  int buf = 0;
  for (int t = 0; t < nt; ++t) {
    if (t + 1 < nt) stage(buf ^ 1, (t + 1) * 32);  // loads fly across compute below
    __builtin_amdgcn_sched_barrier(0);
    s16x8 bf[8], af[4];
#pragma unroll
    for (int g = 0; g < 8; ++g) {
      int r = wn * 128 + g * 16 + l15;
      bf[g] = *(const s16x8*)&lB[buf][r * 32 + (l4 ^ ((r >> 1) & 3)) * 8];
    }
#pragma unroll
    for (int f = 0; f < 4; ++f) {
      int r = wm * 64 + f * 16 + l15;
      af[f] = *(const s16x8*)&lA[buf][r * 32 + (l4 ^ ((r >> 1) & 3)) * 8];
    }
    __builtin_amdgcn_s_setprio(1);
#pragma unroll
    for (int f = 0; f < 4; ++f)
#pragma unroll
      for (int g = 0; g < 8; ++g)
        acc[f][g] = MFMA(af[f], bf[g], acc[f][g], 0, 0, 0);
    __builtin_amdgcn_s_setprio(0);
    __builtin_amdgcn_sched_barrier(0);
    if (t + 1 < nt) {
      asm volatile("s_waitcnt vmcnt(0)" ::: "memory");
      __builtin_amdgcn_s_barrier();
    }
    buf ^= 1;
  }

  const size_t cz = (size_t)blockIdx.z * M * N;
#pragma unroll
  for (int f = 0; f < 4; ++f)
#pragma unroll
    for (int g = 0; g < 8; ++g)
#pragma unroll
      for (int rr = 0; rr < 4; ++rr) {
        int row = bm + wm * 64 + f * 16 + l4 * 4 + rr;
        int col = bn + wn * 128 + g * 16 + l15;
        if (BF16_OUT)
          ((ushort*)Cv)[cz + (size_t)row * N + col] = f2b(acc[f][g][rr]);
        else
          ((float*)Cv)[cz + (size_t)row * N + col] = acc[f][g][rr];
      }
}

// ---------------- GEMM (2-phase, small shapes): C = A*B^T, bf16/f32 out ----------------
template<bool BF16_OUT>
__global__ __launch_bounds__(256, 2)
void gemm_bt(const ushort* __restrict__ A, int lda, const ushort* __restrict__ B, int ldb,
             void* __restrict__ Cv, int M, int N, int Kloop) {
  __shared__ ushort lA[128 * 64];
  __shared__ ushort lB[128 * 64];
  const int nwg = gridDim.x * gridDim.y;
  const int bid = blockIdx.y * gridDim.x + blockIdx.x;
  const int cpx = nwg >> 3;
  const int swz = (bid & 7) * cpx + (bid >> 3);
  const int bm = (swz / gridDim.x) * 128;
  const int bn = (swz % gridDim.x) * 128;
  const int t = threadIdx.x;
  const int lane = t & 63;
  const int w = t >> 6;
  const int wr = (w >> 1) * 64, wc = (w & 1) * 64;
  const int l15 = lane & 15, l4 = lane >> 4;

  f32x4 acc[4][4] = {};

  const ushort* Ag = A + (size_t)blockIdx.z * Kloop +
                     (size_t)(bm + w * 8 + (lane >> 3)) * lda + (lane & 7) * 8;
  const ushort* Bg = B + (size_t)blockIdx.z * Kloop +
                     (size_t)(bn + w * 8 + (lane >> 3)) * ldb + (lane & 7) * 8;
  ushort* lAw = lA + w * 8 * 64;
  ushort* lBw = lB + w * 8 * 64;

  for (int k0 = 0; k0 < Kloop; k0 += 64) {
    __syncthreads();
#pragma unroll
    for (int p = 0; p < 4; ++p) {
      load_lds16(Ag + (size_t)(p * 32) * lda + k0, lAw + p * 32 * 64);
      load_lds16(Bg + (size_t)(p * 32) * ldb + k0, lBw + p * 32 * 64);
    }
    __syncthreads();
#pragma unroll
    for (int kk = 0; kk < 2; ++kk) {
      s16x8 af[4], bf[4];
#pragma unroll
      for (int i = 0; i < 4; ++i)
        af[i] = *(const s16x8*)(lA + (wr + i * 16 + l15) * 64 + kk * 32 + l4 * 8);
#pragma unroll
      for (int j = 0; j < 4; ++j)
        bf[j] = *(const s16x8*)(lB + (wc + j * 16 + l15) * 64 + kk * 32 + l4 * 8);
#pragma unroll
      for (int i = 0; i < 4; ++i)
#pragma unroll
        for (int j = 0; j < 4; ++j)
          acc[i][j] = MFMA(af[i], bf[j], acc[i][j], 0, 0, 0);
    }
  }

  const size_t cz = (size_t)blockIdx.z * M * N;
#pragma unroll
  for (int i = 0; i < 4; ++i)
#pragma unroll
    for (int j = 0; j < 4; ++j)
#pragma unroll
      for (int r = 0; r < 4; ++r) {
        int row = bm + wr + i * 16 + l4 * 4 + r;
        int col = bn + wc + j * 16 + l15;
        if (BF16_OUT)
          ((ushort*)Cv)[cz + (size_t)row * N + col] = f2b(acc[i][j][r]);
        else
          ((float*)Cv)[cz + (size_t)row * N + col] = acc[i][j][r];
      }
}

// ---------------- fused causal GQA attention, QBLK=128, 8 waves ----------------
// Q is read as TWO bf16 split-K partials (qp_b layout) and reduced + rope'd
// in-register: fragment kk and kk+2 hold the rotate-half pair (d, d+64).
__global__ __launch_bounds__(512, 2)
void attn_kernel(const ushort* __restrict__ Qp, const float* __restrict__ cosb,
                 const float* __restrict__ sinb, const ushort* __restrict__ Kb,
                 const ushort* __restrict__ Vt, ushort* __restrict__ O) {
  __shared__ ushort Kl[2][64 * 128];
  __shared__ ushort Vl[2][128 * 64];
  __shared__ ushort Plds[8][16][64];
  const int bx = blockIdx.x;
  const int b = bx >> 8;
  const int qb = b ? (7 - (bx & 7)) : (bx & 7);
  const int h = (bx >> 3) & 31;
  const int kvh = h >> 2;
  const int w = threadIdx.x >> 6;
  const int lane = threadIdx.x & 63;
  const int l15 = lane & 15, l4 = lane >> 4;

  const int q0 = qb * 128 + w * 16;

  s16x8 aq[4];
  {
    const int bs_row = b * 1024 + q0 + l15;
    const ushort* prow0 = Qp + (size_t)bs_row * 4096 + h * 128 + l4 * 8;
    const ushort* prow1 = prow0 + 2048ull * 4096;
    float x[4][8];
#pragma unroll
    for (int kk = 0; kk < 4; ++kk) {
      s16x8 pa = *(const s16x8*)(prow0 + kk * 32);
      s16x8 pb = *(const s16x8*)(prow1 + kk * 32);
#pragma unroll
      for (int j = 0; j < 8; ++j) x[kk][j] = b2f((ushort)pa[j]) + b2f((ushort)pb[j]);
    }
    const float* cb = cosb + ((size_t)bs_row << 6);
    const float* sb = sinb + ((size_t)bs_row << 6);
#pragma unroll
    for (int kk = 0; kk < 2; ++kk)
#pragma unroll
      for (int j = 0; j < 8; ++j) {
        int dd = kk * 32 + l4 * 8 + j;
        float c = cb[dd], s = sb[dd];
        aq[kk][j]     = f2b(x[kk][j] * c - x[kk + 2][j] * s);
        aq[kk + 2][j] = f2b(x[kk + 2][j] * c + x[kk][j] * s);
      }
  }

  auto stageK = [&](int bb, int t) {
#pragma unroll
    for (int i = 0; i < 2; ++i) {
      int row0 = w * 8 + i * 4;
      int row = row0 + (lane >> 4);
      int cg = (lane & 15) ^ (row & 7);
      const ushort* src = Kb + (size_t)(b * 1024 + t * 64 + row) * 1024 + kvh * 128 + cg * 8;
      load_lds16(src, &Kl[bb][row0 * 128]);
    }
  };
  auto stageV = [&](int bb, int t) {
#pragma unroll
    for (int i = 0; i < 2; ++i) {
      int d0 = w * 16 + i * 8;
      int d = d0 + (lane >> 3);
      int cg = (lane & 7) ^ (d & 7);
      const ushort* src = Vt + (size_t)(kvh * 128 + d) * 2048 + b * 1024 + t * 64 + cg * 8;
      load_lds16(src, &Vl[bb][d0 * 64]);
    }
  };

  f32x4 o_acc[8] = {};
  float M_[4] = {-1e30f, -1e30f, -1e30f, -1e30f};
  float L_[4] = {0.f, 0.f, 0.f, 0.f};

  const int nt = 2 * qb + 2;
  int buf = 0;
  stageK(0, 0);
  stageV(0, 0);
  __syncthreads();

  for (int t = 0; t < nt; ++t) {
    if (t + 1 < nt) {
      stageK(buf ^ 1, t + 1);
      stageV(buf ^ 1, t + 1);
    }

    f32x4 s_acc[4] = {};
#pragma unroll
    for (int ns = 0; ns < 4; ++ns) {
      int r = ns * 16 + l15;
#pragma unroll
      for (int kk = 0; kk < 4; ++kk) {
        s16x8 kf = *(const s16x8*)&Kl[buf][r * 128 + (((kk * 4 + l4) ^ (r & 7)) * 8)];
        s_acc[ns] = MFMA(aq[kk], kf, s_acc[ns], 0, 0, 0);
      }
    }

    float p[4][4];
    const bool diag = (t * 64 + 63 > q0);
#pragma unroll
    for (int ns = 0; ns < 4; ++ns)
#pragma unroll
      for (int r = 0; r < 4; ++r) {
        float s = s_acc[ns][r] * 0.08838834764831845f;
        if (diag) {
          int kvi = t * 64 + ns * 16 + l15;
          int qi = q0 + l4 * 4 + r;
          if (kvi > qi) s = -1e30f;
        }
        p[ns][r] = s;
      }

#pragma unroll
    for (int r = 0; r < 4; ++r) {
      float mt = fmaxf(fmaxf(p[0][r], p[1][r]), fmaxf(p[2][r], p[3][r]));
      mt = fmaxf(mt, __shfl_xor(mt, 1));
      mt = fmaxf(mt, __shfl_xor(mt, 2));
      mt = fmaxf(mt, __shfl_xor(mt, 4));
      mt = fmaxf(mt, __shfl_xor(mt, 8));
      float nm = fmaxf(M_[r], mt);
      float sf = __expf(M_[r] - nm);
      M_[r] = nm;
      float ls = 0.f;
#pragma unroll
      for (int ns = 0; ns < 4; ++ns) {
        float e = __expf(p[ns][r] - nm);
        p[ns][r] = e;
        ls += e;
      }
      ls += __shfl_xor(ls, 1);
      ls += __shfl_xor(ls, 2);
      ls += __shfl_xor(ls, 4);
      ls += __shfl_xor(ls, 8);
      L_[r] = L_[r] * sf + ls;
#pragma unroll
      for (int ds_ = 0; ds_ < 8; ++ds_) o_acc[ds_][r] *= sf;
    }

#pragma unroll
    for (int ns = 0; ns < 4; ++ns)
#pragma unroll
      for (int r = 0; r < 4; ++r)
        Plds[w][l4 * 4 + r][ns * 16 + l15] = f2b(p[ns][r]);
    asm volatile("s_waitcnt lgkmcnt(0)" ::: "memory");
    __builtin_amdgcn_sched_barrier(0);
    s16x8 pf[2];
    pf[0] = *(const s16x8*)&Plds[w][l15][l4 * 8];
    pf[1] = *(const s16x8*)&Plds[w][l15][32 + l4 * 8];

#pragma unroll
    for (int ds_ = 0; ds_ < 8; ++ds_) {
      int d = ds_ * 16 + l15;
#pragma unroll
      for (int kk2 = 0; kk2 < 2; ++kk2) {
        s16x8 vf = *(const s16x8*)&Vl[buf][d * 64 + (((kk2 * 4 + l4) ^ (d & 7)) * 8)];
        o_acc[ds_] = MFMA(pf[kk2], vf, o_acc[ds_], 0, 0, 0);
      }
    }

    __syncthreads();
    buf ^= 1;
  }

#pragma unroll
  for (int r = 0; r < 4; ++r) {
    float invl = 1.0f / L_[r];
#pragma unroll
    for (int ds_ = 0; ds_ < 8; ++ds_)
      O[(size_t)(b * 1024 + q0 + l4 * 4 + r) * 4096 + h * 128 + ds_ * 16 + l15] =
          f2b(o_acc[ds_][r] * invl);
  }
}

// ---------------- host ----------------
extern "C" void kernel_launch(void* const* d_in, const int* in_sizes, int n_in,
                              void* d_out, int out_size, void* d_ws, size_t ws_size,
                              hipStream_t stream) {
  const float* hs = (const float*)d_in[0];
  const int* pos = (const int*)d_in[1];
  const float* Wq = (const float*)d_in[2];
  const float* Wdkv = (const float*)d_in[3];
  const float* gam = (const float*)d_in[4];
  const float* bet = (const float*)d_in[5];
  const float* Wuk = (const float*)d_in[6];
  const float* Wuv = (const float*)d_in[7];
  const float* Wo = (const float*)d_in[8];
  float* out = (float*)d_out;

  char* ws = (char*)d_ws;
  size_t off = 0;
  auto alloc = [&](size_t bytes) {
    char* p = ws + off;
    off += (bytes + 255) & ~(size_t)255;
    return p;
  };
  ushort* hs_b = (ushort*)alloc(2048ull * 8192 * 2);
  ushort* Wq_b = (ushort*)alloc(4096ull * 8192 * 2);
  ushort* Wdkv_b = (ushort*)alloc(256ull * 8192 * 2);
  ushort* Wuk_b = (ushort*)alloc(1024ull * 256 * 2);
  ushort* Wuv_b = (ushort*)alloc(1024ull * 256 * 2);
  ushort* Wo_b = (ushort*)alloc(4096ull * 4096 * 2);
  float* cosb = (float*)alloc(2048ull * 64 * 4);
  float* sinb = (float*)alloc(2048ull * 64 * 4);
  float* ckv_part = (float*)alloc(8ull * 2048 * 256 * 4);
  ushort* ckv_b = (ushort*)alloc(2048ull * 256 * 2);
  ushort* qp_b = (ushort*)alloc(2ull * 2048 * 4096 * 2);  // Q bf16 partials; reused for O partials
  ushort* k_b = (ushort*)alloc(2048ull * 1024 * 2);
  ushort* vt_b = (ushort*)alloc(1024ull * 2048 * 2);
  ushort* at_b = (ushort*)alloc(2048ull * 4096 * 2);
  (void)ws_size; (void)in_sizes; (void)n_in; (void)out_size;

  cast6_kernel<<<2048, 256, 0, stream>>>(
      hs, hs_b, (int)(2048ull * 8192 / 8),
      Wq, Wq_b, (int)(4096ull * 8192 / 8),
      Wdkv, Wdkv_b, (int)(256ull * 8192 / 8),
      Wuk, Wuk_b, (int)(1024ull * 256 / 8),
      Wuv, Wuv_b, (int)(1024ull * 256 / 8),
      Wo, Wo_b, (int)(4096ull * 4096 / 8));

  rope_table_kernel<<<512, 256, 0, stream>>>(pos, cosb, sinb);

  // c_kv = LN(hs @ Wdkv^T), split-K=8 + fused reduction in ln_kernel
  gemm_bt<false><<<dim3(2, 16, 8), 256, 0, stream>>>(hs_b, 8192, Wdkv_b, 8192,
                                                     ckv_part, 2048, 256, 1024);
  ln_kernel<<<512, 256, 0, stream>>>(ckv_part, gam, bet, ckv_b);

  // q partials = hs @ Wq^T (split-K=2, bf16); reduce+rope happens inside attn
  gemm2_bt<true><<<dim3(16, 16, 2), 256, 0, stream>>>(hs_b, 8192, Wq_b, 8192,
                                                      qp_b, 2048, 4096, 4096);

  // k = rope(ckv @ Wuk^T), bf16 direct + in-place rope
  gemm_bt<true><<<dim3(8, 16), 256, 0, stream>>>(ckv_b, 256, Wuk_b, 256,
                                                 k_b, 2048, 1024, 256);
  rope_apply_bf16<8><<<2048, 256, 0, stream>>>(k_b, cosb, sinb);

  // v^T = Wuv @ ckv^T  (directly transposed: [1024, 2048] bf16)
  gemm_bt<true><<<dim3(16, 8), 256, 0, stream>>>(Wuv_b, 256, ckv_b, 256,
                                                 vt_b, 1024, 2048, 256);

  // attention (consumes Q partials directly): QBLK=128, 512 blocks, 512 threads
  attn_kernel<<<512, 512, 0, stream>>>(qp_b, cosb, sinb, k_b, vt_b, at_b);

  // out = attn @ Wo^T: split-K=2, bf16 partials into qp_b (free after attn)
  gemm2_bt<true><<<dim3(16, 16, 2), 256, 0, stream>>>(at_b, 4096, Wo_b, 4096,
                                                      qp_b, 2048, 4096, 2048);
  ored_kernel<<<2048, 256, 0, stream>>>(qp_b, out, (int)(2048ull * 4096 / 8));
}

// Round 18
// 438.958 us; speedup vs baseline: 2.6852x; 2.6852x over previous
//
#include <hip/hip_runtime.h>
#include <hip/hip_bf16.h>

using f32x4 = __attribute__((ext_vector_type(4))) float;
using s16x8 = __attribute__((ext_vector_type(8))) short;

#define MFMA __builtin_amdgcn_mfma_f32_16x16x32_bf16

__device__ __forceinline__ ushort f2b(float f) {
  union { float f; unsigned u; } v; v.f = f;
  unsigned r = v.u + 0x7fff + ((v.u >> 16) & 1);
  return (ushort)(r >> 16);
}
__device__ __forceinline__ float b2f(ushort u) {
  union { unsigned u; float f; } v; v.u = ((unsigned)u) << 16;
  return v.f;
}

__device__ __forceinline__ void load_lds16(const ushort* g, ushort* l) {
  __builtin_amdgcn_global_load_lds((const __attribute__((address_space(1))) unsigned int*)g,
                                   (__attribute__((address_space(3))) unsigned int*)l,
                                   16, 0, 0);
}

// ---------------- fused cast f32 -> bf16 for all 6 tensors ----------------
__device__ __forceinline__ void cast_seg(const float* __restrict__ in, ushort* __restrict__ out,
                                         int n8, int tid, int stride) {
  const float4* i4 = (const float4*)in;
  for (int i = tid; i < n8; i += stride) {
    float4 a = i4[i * 2];
    float4 b = i4[i * 2 + 1];
    s16x8 o;
    o[0] = f2b(a.x); o[1] = f2b(a.y); o[2] = f2b(a.z); o[3] = f2b(a.w);
    o[4] = f2b(b.x); o[5] = f2b(b.y); o[6] = f2b(b.z); o[7] = f2b(b.w);
    *(s16x8*)(out + (size_t)i * 8) = o;
  }
}

__global__ void cast6_kernel(const float* a0, ushort* b0, int n0,
                             const float* a1, ushort* b1, int n1,
                             const float* a2, ushort* b2, int n2,
                             const float* a3, ushort* b3, int n3,
                             const float* a4, ushort* b4, int n4,
                             const float* a5, ushort* b5, int n5) {
  int tid = blockIdx.x * blockDim.x + threadIdx.x;
  int stride = gridDim.x * blockDim.x;
  cast_seg(a0, b0, n0, tid, stride);
  cast_seg(a1, b1, n1, tid, stride);
  cast_seg(a2, b2, n2, tid, stride);
  cast_seg(a3, b3, n3, tid, stride);
  cast_seg(a4, b4, n4, tid, stride);
  cast_seg(a5, b5, n5, tid, stride);
}

// ---------------- rope tables: cos/sin per (b,s) row ----------------
__global__ void rope_table_kernel(const int* __restrict__ pos,
                                  float* __restrict__ cosb, float* __restrict__ sinb) {
  int i = blockIdx.x * 256 + threadIdx.x;  // 2048*64
  int d = i & 63;
  float invf = exp2f(-(float)d * (13.287712379549449f / 64.0f));  // 10000^(-d/64)
  float ang = (float)pos[i >> 6] * invf;
  cosb[i] = cosf(ang);
  sinb[i] = sinf(ang);
}

// ---------------- layernorm over 256 cols with 8-way split-K reduction ----------------
__global__ void ln_kernel(const float* __restrict__ X, const float* __restrict__ gamma,
                          const float* __restrict__ beta, ushort* __restrict__ out) {
  int row = blockIdx.x * 4 + (threadIdx.x >> 6);
  int lane = threadIdx.x & 63;
  float4 x = {0.f, 0.f, 0.f, 0.f};
#pragma unroll
  for (int sp = 0; sp < 8; ++sp) {
    const float4 t = *(const float4*)(X + (size_t)sp * 2048 * 256 + (size_t)row * 256 + lane * 4);
    x.x += t.x; x.y += t.y; x.z += t.z; x.w += t.w;
  }
  float s = x.x + x.y + x.z + x.w;
  for (int m = 32; m >= 1; m >>= 1) s += __shfl_xor(s, m);
  float mu = s * (1.0f / 256.0f);
  float dx = x.x - mu, dy = x.y - mu, dz = x.z - mu, dw = x.w - mu;
  float v = dx * dx + dy * dy + dz * dz + dw * dw;
  for (int m = 32; m >= 1; m >>= 1) v += __shfl_xor(v, m);
  float inv = rsqrtf(v * (1.0f / 256.0f) + 1e-5f);
  const float4 g = *(const float4*)(gamma + lane * 4);
  const float4 bt = *(const float4*)(beta + lane * 4);
  ushort4 o;
  o.x = f2b(dx * inv * g.x + bt.x);
  o.y = f2b(dy * inv * g.y + bt.y);
  o.z = f2b(dz * inv * g.z + bt.z);
  o.w = f2b(dw * inv * g.w + bt.w);
  *(ushort4*)(out + (size_t)row * 256 + lane * 4) = o;
}

// ---------------- rope apply in-place on bf16 [2048, NH*128] ----------------
template<int NH>
__global__ void rope_apply_bf16(ushort* __restrict__ X, const float* __restrict__ cosb,
                                const float* __restrict__ sinb) {
  int bs = blockIdx.x;
  ushort* xr = X + (size_t)bs * (NH * 128);
  int p = threadIdx.x;
  if (p < NH * 8) {
    int h = p >> 3, c8 = p & 7;
    int idx = h * 128 + c8 * 8;
    s16x8 x1 = *(s16x8*)(xr + idx);
    s16x8 x2 = *(s16x8*)(xr + idx + 64);
    const float* cb = cosb + (bs << 6) + c8 * 8;
    const float* sb = sinb + (bs << 6) + c8 * 8;
    s16x8 o1, o2;
#pragma unroll
    for (int j = 0; j < 8; ++j) {
      float a = b2f((ushort)x1[j]), bb = b2f((ushort)x2[j]);
      float c = cb[j], s = sb[j];
      o1[j] = f2b(a * c - bb * s);
      o2[j] = f2b(bb * c + a * s);
    }
    *(s16x8*)(xr + idx) = o1;
    *(s16x8*)(xr + idx + 64) = o2;
  }
}

// ---------------- O split-K reduce: out = p0 + p1 (bf16 partials -> f32) ----------------
__global__ void ored_kernel(const ushort* __restrict__ P, float* __restrict__ out, int n8) {
  int stride = gridDim.x * blockDim.x;
  for (int i = blockIdx.x * blockDim.x + threadIdx.x; i < n8; i += stride) {
    s16x8 a = *(const s16x8*)(P + (size_t)i * 8);
    s16x8 b = *(const s16x8*)(P + 2048ull * 4096 + (size_t)i * 8);
    float4 o0, o1;
    o0.x = b2f((ushort)a[0]) + b2f((ushort)b[0]);
    o0.y = b2f((ushort)a[1]) + b2f((ushort)b[1]);
    o0.z = b2f((ushort)a[2]) + b2f((ushort)b[2]);
    o0.w = b2f((ushort)a[3]) + b2f((ushort)b[3]);
    o1.x = b2f((ushort)a[4]) + b2f((ushort)b[4]);
    o1.y = b2f((ushort)a[5]) + b2f((ushort)b[5]);
    o1.z = b2f((ushort)a[6]) + b2f((ushort)b[6]);
    o1.w = b2f((ushort)a[7]) + b2f((ushort)b[7]);
    ((float4*)out)[i * 2] = o0;
    ((float4*)out)[i * 2 + 1] = o1;
  }
}

// ---------------- pipelined GEMM: C[M,N] = A[M,K]*B[N,K]^T ----------------
// 256 threads = 4 waves (2M x 2N), tile 128(M) x 256(N), BK=32; per-wave 64x128.
// Triple-buffered LDS (72KB -> 2 blocks/CU), counted s_waitcnt vmcnt(6) + raw
// s_barrier (no vmcnt(0) drain in steady state). Both-sides chunk-XOR swizzle
// ^((r>>1)&3): 0 bank conflicts (measured r15).
// NOTE: do NOT raise launch_bounds min-waves: acc[4][8]=128 VGPRs; a 3-waves/SIMD
// cap spills accumulators to scratch (r17: WRITE_SIZE 33MB->585MB, 2.9x slower).
template<bool BF16_OUT>
__global__ __launch_bounds__(256, 2)
void gemm2_bt(const ushort* __restrict__ A, int lda, const ushort* __restrict__ B, int ldb,
              void* __restrict__ Cv, int M, int N, int Kloop) {
  __shared__ ushort lA[3][128 * 32];
  __shared__ ushort lB[3][256 * 32];
  const int gx = gridDim.x;
  const int nwg = gx * gridDim.y;
  const int bid = blockIdx.y * gx + blockIdx.x;
  const int cpx = nwg >> 3;
  const int swz = (bid & 7) * cpx + (bid >> 3);
  const int bm = (swz / gx) * 128;
  const int bn = (swz % gx) * 256;
  const int lane = threadIdx.x & 63;
  const int w = threadIdx.x >> 6;
  const int wm = w >> 1, wn = w & 1;
  const int l15 = lane & 15, l4 = lane >> 4;
  const int lr = lane >> 2;
  const int lc = lane & 3;

  f32x4 acc[4][8] = {};

  const ushort* Abase = A + (size_t)blockIdx.z * Kloop;
  const ushort* Bbase = B + (size_t)blockIdx.z * Kloop;

  auto stage = [&](int bb, int k0) {
#pragma unroll
    for (int p = 0; p < 2; ++p) {
      int row0 = w * 32 + p * 16;
      int r = row0 + lr;
      const ushort* src = Abase + (size_t)(bm + r) * lda + k0 + (lc ^ ((r >> 1) & 3)) * 8;
      load_lds16(src, &lA[bb][row0 * 32]);
    }
#pragma unroll
    for (int p = 0; p < 4; ++p) {
      int row0 = w * 64 + p * 16;
      int r = row0 + lr;
      const ushort* src = Bbase + (size_t)(bn + r) * ldb + k0 + (lc ^ ((r >> 1) & 3)) * 8;
      load_lds16(src, &lB[bb][row0 * 32]);
    }
  };

  const int nt = Kloop / 32;
  stage(0, 0);
  stage(1, 32);
  asm volatile("s_waitcnt vmcnt(6)" ::: "memory");
  __builtin_amdgcn_s_barrier();

  int cur = 0;
  for (int t = 0; t < nt; ++t) {
    if (t + 2 < nt) stage(cur == 0 ? 2 : cur - 1, (t + 2) * 32);
    __builtin_amdgcn_sched_barrier(0);
    s16x8 bf[8], af[4];
#pragma unroll
    for (int g = 0; g < 8; ++g) {
      int r = wn * 128 + g * 16 + l15;
      bf[g] = *(const s16x8*)&lB[cur][r * 32 + (l4 ^ ((r >> 1) & 3)) * 8];
    }
#pragma unroll
    for (int f = 0; f < 4; ++f) {
      int r = wm * 64 + f * 16 + l15;
      af[f] = *(const s16x8*)&lA[cur][r * 32 + (l4 ^ ((r >> 1) & 3)) * 8];
    }
    __builtin_amdgcn_s_setprio(1);
#pragma unroll
    for (int f = 0; f < 4; ++f)
#pragma unroll
      for (int g = 0; g < 8; ++g)
        acc[f][g] = MFMA(af[f], bf[g], acc[f][g], 0, 0, 0);
    __builtin_amdgcn_s_setprio(0);
    __builtin_amdgcn_sched_barrier(0);
    if (t + 1 < nt) {
      if (t + 2 < nt) asm volatile("s_waitcnt vmcnt(6)" ::: "memory");
      else            asm volatile("s_waitcnt vmcnt(0)" ::: "memory");
      __builtin_amdgcn_s_barrier();
    }
    cur = (cur == 2) ? 0 : cur + 1;
  }

  const size_t cz = (size_t)blockIdx.z * M * N;
#pragma unroll
  for (int f = 0; f < 4; ++f)
#pragma unroll
    for (int g = 0; g < 8; ++g)
#pragma unroll
      for (int rr = 0; rr < 4; ++rr) {
        int row = bm + wm * 64 + f * 16 + l4 * 4 + rr;
        int col = bn + wn * 128 + g * 16 + l15;
        if (BF16_OUT)
          ((ushort*)Cv)[cz + (size_t)row * N + col] = f2b(acc[f][g][rr]);
        else
          ((float*)Cv)[cz + (size_t)row * N + col] = acc[f][g][rr];
      }
}

// ---------------- GEMM (2-phase, small shapes): C = A*B^T, bf16/f32 out ----------------
template<bool BF16_OUT>
__global__ __launch_bounds__(256, 2)
void gemm_bt(const ushort* __restrict__ A, int lda, const ushort* __restrict__ B, int ldb,
             void* __restrict__ Cv, int M, int N, int Kloop) {
  __shared__ ushort lA[128 * 64];
  __shared__ ushort lB[128 * 64];
  const int nwg = gridDim.x * gridDim.y;
  const int bid = blockIdx.y * gridDim.x + blockIdx.x;
  const int cpx = nwg >> 3;
  const int swz = (bid & 7) * cpx + (bid >> 3);
  const int bm = (swz / gridDim.x) * 128;
  const int bn = (swz % gridDim.x) * 128;
  const int t = threadIdx.x;
  const int lane = t & 63;
  const int w = t >> 6;
  const int wr = (w >> 1) * 64, wc = (w & 1) * 64;
  const int l15 = lane & 15, l4 = lane >> 4;

  f32x4 acc[4][4] = {};

  const ushort* Ag = A + (size_t)blockIdx.z * Kloop +
                     (size_t)(bm + w * 8 + (lane >> 3)) * lda + (lane & 7) * 8;
  const ushort* Bg = B + (size_t)blockIdx.z * Kloop +
                     (size_t)(bn + w * 8 + (lane >> 3)) * ldb + (lane & 7) * 8;
  ushort* lAw = lA + w * 8 * 64;
  ushort* lBw = lB + w * 8 * 64;

  for (int k0 = 0; k0 < Kloop; k0 += 64) {
    __syncthreads();
#pragma unroll
    for (int p = 0; p < 4; ++p) {
      load_lds16(Ag + (size_t)(p * 32) * lda + k0, lAw + p * 32 * 64);
      load_lds16(Bg + (size_t)(p * 32) * ldb + k0, lBw + p * 32 * 64);
    }
    __syncthreads();
#pragma unroll
    for (int kk = 0; kk < 2; ++kk) {
      s16x8 af[4], bf[4];
#pragma unroll
      for (int i = 0; i < 4; ++i)
        af[i] = *(const s16x8*)(lA + (wr + i * 16 + l15) * 64 + kk * 32 + l4 * 8);
#pragma unroll
      for (int j = 0; j < 4; ++j)
        bf[j] = *(const s16x8*)(lB + (wc + j * 16 + l15) * 64 + kk * 32 + l4 * 8);
#pragma unroll
      for (int i = 0; i < 4; ++i)
#pragma unroll
        for (int j = 0; j < 4; ++j)
          acc[i][j] = MFMA(af[i], bf[j], acc[i][j], 0, 0, 0);
    }
  }

  const size_t cz = (size_t)blockIdx.z * M * N;
#pragma unroll
  for (int i = 0; i < 4; ++i)
#pragma unroll
    for (int j = 0; j < 4; ++j)
#pragma unroll
      for (int r = 0; r < 4; ++r) {
        int row = bm + wr + i * 16 + l4 * 4 + r;
        int col = bn + wc + j * 16 + l15;
        if (BF16_OUT)
          ((ushort*)Cv)[cz + (size_t)row * N + col] = f2b(acc[i][j][r]);
        else
          ((float*)Cv)[cz + (size_t)row * N + col] = acc[i][j][r];
      }
}

// ---------------- fused causal GQA attention, QBLK=128, 8 waves ----------------
// Q is read as TWO bf16 split-K partials (qp_b layout) and reduced + rope'd
// in-register: fragment kk and kk+2 hold the rotate-half pair (d, d+64).
__global__ __launch_bounds__(512, 2)
void attn_kernel(const ushort* __restrict__ Qp, const float* __restrict__ cosb,
                 const float* __restrict__ sinb, const ushort* __restrict__ Kb,
                 const ushort* __restrict__ Vt, ushort* __restrict__ O) {
  __shared__ ushort Kl[2][64 * 128];
  __shared__ ushort Vl[2][128 * 64];
  __shared__ ushort Plds[8][16][64];
  const int bx = blockIdx.x;
  const int b = bx >> 8;
  const int qb = b ? (7 - (bx & 7)) : (bx & 7);
  const int h = (bx >> 3) & 31;
  const int kvh = h >> 2;
  const int w = threadIdx.x >> 6;
  const int lane = threadIdx.x & 63;
  const int l15 = lane & 15, l4 = lane >> 4;

  const int q0 = qb * 128 + w * 16;

  s16x8 aq[4];
  {
    const int bs_row = b * 1024 + q0 + l15;
    const ushort* prow0 = Qp + (size_t)bs_row * 4096 + h * 128 + l4 * 8;
    const ushort* prow1 = prow0 + 2048ull * 4096;
    float x[4][8];
#pragma unroll
    for (int kk = 0; kk < 4; ++kk) {
      s16x8 pa = *(const s16x8*)(prow0 + kk * 32);
      s16x8 pb = *(const s16x8*)(prow1 + kk * 32);
#pragma unroll
      for (int j = 0; j < 8; ++j) x[kk][j] = b2f((ushort)pa[j]) + b2f((ushort)pb[j]);
    }
    const float* cb = cosb + ((size_t)bs_row << 6);
    const float* sb = sinb + ((size_t)bs_row << 6);
#pragma unroll
    for (int kk = 0; kk < 2; ++kk)
#pragma unroll
      for (int j = 0; j < 8; ++j) {
        int dd = kk * 32 + l4 * 8 + j;
        float c = cb[dd], s = sb[dd];
        aq[kk][j]     = f2b(x[kk][j] * c - x[kk + 2][j] * s);
        aq[kk + 2][j] = f2b(x[kk + 2][j] * c + x[kk][j] * s);
      }
  }

  auto stageK = [&](int bb, int t) {
#pragma unroll
    for (int i = 0; i < 2; ++i) {
      int row0 = w * 8 + i * 4;
      int row = row0 + (lane >> 4);
      int cg = (lane & 15) ^ (row & 7);
      const ushort* src = Kb + (size_t)(b * 1024 + t * 64 + row) * 1024 + kvh * 128 + cg * 8;
      load_lds16(src, &Kl[bb][row0 * 128]);
    }
  };
  auto stageV = [&](int bb, int t) {
#pragma unroll
    for (int i = 0; i < 2; ++i) {
      int d0 = w * 16 + i * 8;
      int d = d0 + (lane >> 3);
      int cg = (lane & 7) ^ (d & 7);
      const ushort* src = Vt + (size_t)(kvh * 128 + d) * 2048 + b * 1024 + t * 64 + cg * 8;
      load_lds16(src, &Vl[bb][d0 * 64]);
    }
  };

  f32x4 o_acc[8] = {};
  float M_[4] = {-1e30f, -1e30f, -1e30f, -1e30f};
  float L_[4] = {0.f, 0.f, 0.f, 0.f};

  const int nt = 2 * qb + 2;
  int buf = 0;
  stageK(0, 0);
  stageV(0, 0);
  __syncthreads();

  for (int t = 0; t < nt; ++t) {
    if (t + 1 < nt) {
      stageK(buf ^ 1, t + 1);
      stageV(buf ^ 1, t + 1);
    }

    f32x4 s_acc[4] = {};
#pragma unroll
    for (int ns = 0; ns < 4; ++ns) {
      int r = ns * 16 + l15;
#pragma unroll
      for (int kk = 0; kk < 4; ++kk) {
        s16x8 kf = *(const s16x8*)&Kl[buf][r * 128 + (((kk * 4 + l4) ^ (r & 7)) * 8)];
        s_acc[ns] = MFMA(aq[kk], kf, s_acc[ns], 0, 0, 0);
      }
    }

    float p[4][4];
    const bool diag = (t * 64 + 63 > q0);
#pragma unroll
    for (int ns = 0; ns < 4; ++ns)
#pragma unroll
      for (int r = 0; r < 4; ++r) {
        float s = s_acc[ns][r] * 0.08838834764831845f;
        if (diag) {
          int kvi = t * 64 + ns * 16 + l15;
          int qi = q0 + l4 * 4 + r;
          if (kvi > qi) s = -1e30f;
        }
        p[ns][r] = s;
      }

#pragma unroll
    for (int r = 0; r < 4; ++r) {
      float mt = fmaxf(fmaxf(p[0][r], p[1][r]), fmaxf(p[2][r], p[3][r]));
      mt = fmaxf(mt, __shfl_xor(mt, 1));
      mt = fmaxf(mt, __shfl_xor(mt, 2));
      mt = fmaxf(mt, __shfl_xor(mt, 4));
      mt = fmaxf(mt, __shfl_xor(mt, 8));
      float nm = fmaxf(M_[r], mt);
      float sf = __expf(M_[r] - nm);
      M_[r] = nm;
      float ls = 0.f;
#pragma unroll
      for (int ns = 0; ns < 4; ++ns) {
        float e = __expf(p[ns][r] - nm);
        p[ns][r] = e;
        ls += e;
      }
      ls += __shfl_xor(ls, 1);
      ls += __shfl_xor(ls, 2);
      ls += __shfl_xor(ls, 4);
      ls += __shfl_xor(ls, 8);
      L_[r] = L_[r] * sf + ls;
#pragma unroll
      for (int ds_ = 0; ds_ < 8; ++ds_) o_acc[ds_][r] *= sf;
    }

#pragma unroll
    for (int ns = 0; ns < 4; ++ns)
#pragma unroll
      for (int r = 0; r < 4; ++r)
        Plds[w][l4 * 4 + r][ns * 16 + l15] = f2b(p[ns][r]);
    asm volatile("s_waitcnt lgkmcnt(0)" ::: "memory");
    __builtin_amdgcn_sched_barrier(0);
    s16x8 pf[2];
    pf[0] = *(const s16x8*)&Plds[w][l15][l4 * 8];
    pf[1] = *(const s16x8*)&Plds[w][l15][32 + l4 * 8];

#pragma unroll
    for (int ds_ = 0; ds_ < 8; ++ds_) {
      int d = ds_ * 16 + l15;
#pragma unroll
      for (int kk2 = 0; kk2 < 2; ++kk2) {
        s16x8 vf = *(const s16x8*)&Vl[buf][d * 64 + (((kk2 * 4 + l4) ^ (d & 7)) * 8)];
        o_acc[ds_] = MFMA(pf[kk2], vf, o_acc[ds_], 0, 0, 0);
      }
    }

    __syncthreads();
    buf ^= 1;
  }

#pragma unroll
  for (int r = 0; r < 4; ++r) {
    float invl = 1.0f / L_[r];
#pragma unroll
    for (int ds_ = 0; ds_ < 8; ++ds_)
      O[(size_t)(b * 1024 + q0 + l4 * 4 + r) * 4096 + h * 128 + ds_ * 16 + l15] =
          f2b(o_acc[ds_][r] * invl);
  }
}

// ---------------- host ----------------
extern "C" void kernel_launch(void* const* d_in, const int* in_sizes, int n_in,
                              void* d_out, int out_size, void* d_ws, size_t ws_size,
                              hipStream_t stream) {
  const float* hs = (const float*)d_in[0];
  const int* pos = (const int*)d_in[1];
  const float* Wq = (const float*)d_in[2];
  const float* Wdkv = (const float*)d_in[3];
  const float* gam = (const float*)d_in[4];
  const float* bet = (const float*)d_in[5];
  const float* Wuk = (const float*)d_in[6];
  const float* Wuv = (const float*)d_in[7];
  const float* Wo = (const float*)d_in[8];
  float* out = (float*)d_out;

  char* ws = (char*)d_ws;
  size_t off = 0;
  auto alloc = [&](size_t bytes) {
    char* p = ws + off;
    off += (bytes + 255) & ~(size_t)255;
    return p;
  };
  ushort* hs_b = (ushort*)alloc(2048ull * 8192 * 2);
  ushort* Wq_b = (ushort*)alloc(4096ull * 8192 * 2);
  ushort* Wdkv_b = (ushort*)alloc(256ull * 8192 * 2);
  ushort* Wuk_b = (ushort*)alloc(1024ull * 256 * 2);
  ushort* Wuv_b = (ushort*)alloc(1024ull * 256 * 2);
  ushort* Wo_b = (ushort*)alloc(4096ull * 4096 * 2);
  float* cosb = (float*)alloc(2048ull * 64 * 4);
  float* sinb = (float*)alloc(2048ull * 64 * 4);
  float* ckv_part = (float*)alloc(8ull * 2048 * 256 * 4);
  ushort* ckv_b = (ushort*)alloc(2048ull * 256 * 2);
  ushort* qp_b = (ushort*)alloc(2ull * 2048 * 4096 * 2);  // Q bf16 partials; reused for O partials
  ushort* k_b = (ushort*)alloc(2048ull * 1024 * 2);
  ushort* vt_b = (ushort*)alloc(1024ull * 2048 * 2);
  ushort* at_b = (ushort*)alloc(2048ull * 4096 * 2);
  (void)ws_size; (void)in_sizes; (void)n_in; (void)out_size;

  cast6_kernel<<<2048, 256, 0, stream>>>(
      hs, hs_b, (int)(2048ull * 8192 / 8),
      Wq, Wq_b, (int)(4096ull * 8192 / 8),
      Wdkv, Wdkv_b, (int)(256ull * 8192 / 8),
      Wuk, Wuk_b, (int)(1024ull * 256 / 8),
      Wuv, Wuv_b, (int)(1024ull * 256 / 8),
      Wo, Wo_b, (int)(4096ull * 4096 / 8));

  rope_table_kernel<<<512, 256, 0, stream>>>(pos, cosb, sinb);

  // c_kv = LN(hs @ Wdkv^T), split-K=8 + fused reduction in ln_kernel
  gemm_bt<false><<<dim3(2, 16, 8), 256, 0, stream>>>(hs_b, 8192, Wdkv_b, 8192,
                                                     ckv_part, 2048, 256, 1024);
  ln_kernel<<<512, 256, 0, stream>>>(ckv_part, gam, bet, ckv_b);

  // q partials = hs @ Wq^T (split-K=2, bf16); reduce+rope happens inside attn
  gemm2_bt<true><<<dim3(16, 16, 2), 256, 0, stream>>>(hs_b, 8192, Wq_b, 8192,
                                                      qp_b, 2048, 4096, 4096);

  // k = rope(ckv @ Wuk^T), bf16 direct + in-place rope
  gemm_bt<true><<<dim3(8, 16), 256, 0, stream>>>(ckv_b, 256, Wuk_b, 256,
                                                 k_b, 2048, 1024, 256);
  rope_apply_bf16<8><<<2048, 256, 0, stream>>>(k_b, cosb, sinb);

  // v^T = Wuv @ ckv^T  (directly transposed: [1024, 2048] bf16)
  gemm_bt<true><<<dim3(16, 8), 256, 0, stream>>>(Wuv_b, 256, ckv_b, 256,
                                                 vt_b, 1024, 2048, 256);

  // attention (consumes Q partials directly): QBLK=128, 512 blocks, 512 threads
  attn_kernel<<<512, 512, 0, stream>>>(qp_b, cosb, sinb, k_b, vt_b, at_b);

  // out = attn @ Wo^T: split-K=2, bf16 partials into qp_b (free after attn)
  gemm2_bt<true><<<dim3(16, 16, 2), 256, 0, stream>>>(at_b, 4096, Wo_b, 4096,
                                                      qp_b, 2048, 4096, 2048);
  ored_kernel<<<2048, 256, 0, stream>>>(qp_b, out, (int)(2048ull * 4096 / 8));
}

// Round 19
// 435.957 us; speedup vs baseline: 2.7037x; 1.0069x over previous
//
#include <hip/hip_runtime.h>
#include <hip/hip_bf16.h>

using f32x4 = __attribute__((ext_vector_type(4))) float;
using s16x8 = __attribute__((ext_vector_type(8))) short;

#define MFMA __builtin_amdgcn_mfma_f32_16x16x32_bf16

__device__ __forceinline__ ushort f2b(float f) {
  union { float f; unsigned u; } v; v.f = f;
  unsigned r = v.u + 0x7fff + ((v.u >> 16) & 1);
  return (ushort)(r >> 16);
}
__device__ __forceinline__ float b2f(ushort u) {
  union { unsigned u; float f; } v; v.u = ((unsigned)u) << 16;
  return v.f;
}

__device__ __forceinline__ void load_lds16(const ushort* g, ushort* l) {
  __builtin_amdgcn_global_load_lds((const __attribute__((address_space(1))) unsigned int*)g,
                                   (__attribute__((address_space(3))) unsigned int*)l,
                                   16, 0, 0);
}

// ---------------- fused: cast f32 -> bf16 for 6 tensors + rope tables ----------------
__device__ __forceinline__ void cast_seg(const float* __restrict__ in, ushort* __restrict__ out,
                                         int n8, int tid, int stride) {
  const float4* i4 = (const float4*)in;
  for (int i = tid; i < n8; i += stride) {
    float4 a = i4[i * 2];
    float4 b = i4[i * 2 + 1];
    s16x8 o;
    o[0] = f2b(a.x); o[1] = f2b(a.y); o[2] = f2b(a.z); o[3] = f2b(a.w);
    o[4] = f2b(b.x); o[5] = f2b(b.y); o[6] = f2b(b.z); o[7] = f2b(b.w);
    *(s16x8*)(out + (size_t)i * 8) = o;
  }
}

__global__ void cast6_kernel(const float* a0, ushort* b0, int n0,
                             const float* a1, ushort* b1, int n1,
                             const float* a2, ushort* b2, int n2,
                             const float* a3, ushort* b3, int n3,
                             const float* a4, ushort* b4, int n4,
                             const float* a5, ushort* b5, int n5,
                             const int* __restrict__ pos,
                             float* __restrict__ cosb, float* __restrict__ sinb) {
  int tid = blockIdx.x * blockDim.x + threadIdx.x;
  int stride = gridDim.x * blockDim.x;
  // rope tables: 2048*64 entries
  for (int i = tid; i < 2048 * 64; i += stride) {
    int d = i & 63;
    float invf = exp2f(-(float)d * (13.287712379549449f / 64.0f));  // 10000^(-d/64)
    float ang = (float)pos[i >> 6] * invf;
    cosb[i] = cosf(ang);
    sinb[i] = sinf(ang);
  }
  cast_seg(a0, b0, n0, tid, stride);
  cast_seg(a1, b1, n1, tid, stride);
  cast_seg(a2, b2, n2, tid, stride);
  cast_seg(a3, b3, n3, tid, stride);
  cast_seg(a4, b4, n4, tid, stride);
  cast_seg(a5, b5, n5, tid, stride);
}

// ---------------- layernorm over 256 cols with 8-way split-K reduction ----------------
__global__ void ln_kernel(const float* __restrict__ X, const float* __restrict__ gamma,
                          const float* __restrict__ beta, ushort* __restrict__ out) {
  int row = blockIdx.x * 4 + (threadIdx.x >> 6);
  int lane = threadIdx.x & 63;
  float4 x = {0.f, 0.f, 0.f, 0.f};
#pragma unroll
  for (int sp = 0; sp < 8; ++sp) {
    const float4 t = *(const float4*)(X + (size_t)sp * 2048 * 256 + (size_t)row * 256 + lane * 4);
    x.x += t.x; x.y += t.y; x.z += t.z; x.w += t.w;
  }
  float s = x.x + x.y + x.z + x.w;
  for (int m = 32; m >= 1; m >>= 1) s += __shfl_xor(s, m);
  float mu = s * (1.0f / 256.0f);
  float dx = x.x - mu, dy = x.y - mu, dz = x.z - mu, dw = x.w - mu;
  float v = dx * dx + dy * dy + dz * dz + dw * dw;
  for (int m = 32; m >= 1; m >>= 1) v += __shfl_xor(v, m);
  float inv = rsqrtf(v * (1.0f / 256.0f) + 1e-5f);
  const float4 g = *(const float4*)(gamma + lane * 4);
  const float4 bt = *(const float4*)(beta + lane * 4);
  ushort4 o;
  o.x = f2b(dx * inv * g.x + bt.x);
  o.y = f2b(dy * inv * g.y + bt.y);
  o.z = f2b(dz * inv * g.z + bt.z);
  o.w = f2b(dw * inv * g.w + bt.w);
  *(ushort4*)(out + (size_t)row * 256 + lane * 4) = o;
}

// ---------------- rope apply in-place on bf16 [2048, NH*128] ----------------
template<int NH>
__global__ void rope_apply_bf16(ushort* __restrict__ X, const float* __restrict__ cosb,
                                const float* __restrict__ sinb) {
  int bs = blockIdx.x;
  ushort* xr = X + (size_t)bs * (NH * 128);
  int p = threadIdx.x;
  if (p < NH * 8) {
    int h = p >> 3, c8 = p & 7;
    int idx = h * 128 + c8 * 8;
    s16x8 x1 = *(s16x8*)(xr + idx);
    s16x8 x2 = *(s16x8*)(xr + idx + 64);
    const float* cb = cosb + (bs << 6) + c8 * 8;
    const float* sb = sinb + (bs << 6) + c8 * 8;
    s16x8 o1, o2;
#pragma unroll
    for (int j = 0; j < 8; ++j) {
      float a = b2f((ushort)x1[j]), bb = b2f((ushort)x2[j]);
      float c = cb[j], s = sb[j];
      o1[j] = f2b(a * c - bb * s);
      o2[j] = f2b(bb * c + a * s);
    }
    *(s16x8*)(xr + idx) = o1;
    *(s16x8*)(xr + idx + 64) = o2;
  }
}

// ---------------- O split-K reduce: out = p0 + p1 (bf16 partials -> f32) ----------------
__global__ void ored_kernel(const ushort* __restrict__ P, float* __restrict__ out, int n8) {
  int stride = gridDim.x * blockDim.x;
  for (int i = blockIdx.x * blockDim.x + threadIdx.x; i < n8; i += stride) {
    s16x8 a = *(const s16x8*)(P + (size_t)i * 8);
    s16x8 b = *(const s16x8*)(P + 2048ull * 4096 + (size_t)i * 8);
    float4 o0, o1;
    o0.x = b2f((ushort)a[0]) + b2f((ushort)b[0]);
    o0.y = b2f((ushort)a[1]) + b2f((ushort)b[1]);
    o0.z = b2f((ushort)a[2]) + b2f((ushort)b[2]);
    o0.w = b2f((ushort)a[3]) + b2f((ushort)b[3]);
    o1.x = b2f((ushort)a[4]) + b2f((ushort)b[4]);
    o1.y = b2f((ushort)a[5]) + b2f((ushort)b[5]);
    o1.z = b2f((ushort)a[6]) + b2f((ushort)b[6]);
    o1.w = b2f((ushort)a[7]) + b2f((ushort)b[7]);
    ((float4*)out)[i * 2] = o0;
    ((float4*)out)[i * 2 + 1] = o1;
  }
}

// ---------------- pipelined GEMM: C[M,N] = A[M,K]*B[N,K]^T ----------------
// 256 threads = 4 waves (2M x 2N), tile 128(M) x 256(N), BK=32; per-wave 64x128.
// Triple-buffered LDS (72KB -> 2 blocks/CU), counted s_waitcnt vmcnt(6) + raw
// s_barrier (no vmcnt(0) drain in steady state). Both-sides chunk-XOR swizzle
// ^((r>>1)&3): 0 bank conflicts (measured r15).
// NOTE: do NOT raise launch_bounds min-waves: acc[4][8]=128 VGPRs; a 3-waves/SIMD
// cap spills accumulators to scratch (r17: WRITE_SIZE 33MB->585MB, 2.9x slower).
template<bool BF16_OUT>
__global__ __launch_bounds__(256, 2)
void gemm2_bt(const ushort* __restrict__ A, int lda, const ushort* __restrict__ B, int ldb,
              void* __restrict__ Cv, int M, int N, int Kloop) {
  __shared__ ushort lA[3][128 * 32];
  __shared__ ushort lB[3][256 * 32];
  const int gx = gridDim.x;
  const int nwg = gx * gridDim.y;
  const int bid = blockIdx.y * gx + blockIdx.x;
  const int cpx = nwg >> 3;
  const int swz = (bid & 7) * cpx + (bid >> 3);
  const int bm = (swz / gx) * 128;
  const int bn = (swz % gx) * 256;
  const int lane = threadIdx.x & 63;
  const int w = threadIdx.x >> 6;
  const int wm = w >> 1, wn = w & 1;
  const int l15 = lane & 15, l4 = lane >> 4;
  const int lr = lane >> 2;
  const int lc = lane & 3;

  f32x4 acc[4][8] = {};

  const ushort* Abase = A + (size_t)blockIdx.z * Kloop;
  const ushort* Bbase = B + (size_t)blockIdx.z * Kloop;

  auto stage = [&](int bb, int k0) {
#pragma unroll
    for (int p = 0; p < 2; ++p) {
      int row0 = w * 32 + p * 16;
      int r = row0 + lr;
      const ushort* src = Abase + (size_t)(bm + r) * lda + k0 + (lc ^ ((r >> 1) & 3)) * 8;
      load_lds16(src, &lA[bb][row0 * 32]);
    }
#pragma unroll
    for (int p = 0; p < 4; ++p) {
      int row0 = w * 64 + p * 16;
      int r = row0 + lr;
      const ushort* src = Bbase + (size_t)(bn + r) * ldb + k0 + (lc ^ ((r >> 1) & 3)) * 8;
      load_lds16(src, &lB[bb][row0 * 32]);
    }
  };

  const int nt = Kloop / 32;
  stage(0, 0);
  stage(1, 32);
  asm volatile("s_waitcnt vmcnt(6)" ::: "memory");
  __builtin_amdgcn_s_barrier();

  int cur = 0;
  for (int t = 0; t < nt; ++t) {
    if (t + 2 < nt) stage(cur == 0 ? 2 : cur - 1, (t + 2) * 32);
    __builtin_amdgcn_sched_barrier(0);
    s16x8 bf[8], af[4];
#pragma unroll
    for (int g = 0; g < 8; ++g) {
      int r = wn * 128 + g * 16 + l15;
      bf[g] = *(const s16x8*)&lB[cur][r * 32 + (l4 ^ ((r >> 1) & 3)) * 8];
    }
#pragma unroll
    for (int f = 0; f < 4; ++f) {
      int r = wm * 64 + f * 16 + l15;
      af[f] = *(const s16x8*)&lA[cur][r * 32 + (l4 ^ ((r >> 1) & 3)) * 8];
    }
    __builtin_amdgcn_s_setprio(1);
#pragma unroll
    for (int f = 0; f < 4; ++f)
#pragma unroll
      for (int g = 0; g < 8; ++g)
        acc[f][g] = MFMA(af[f], bf[g], acc[f][g], 0, 0, 0);
    __builtin_amdgcn_s_setprio(0);
    __builtin_amdgcn_sched_barrier(0);
    if (t + 1 < nt) {
      if (t + 2 < nt) asm volatile("s_waitcnt vmcnt(6)" ::: "memory");
      else            asm volatile("s_waitcnt vmcnt(0)" ::: "memory");
      __builtin_amdgcn_s_barrier();
    }
    cur = (cur == 2) ? 0 : cur + 1;
  }

  const size_t cz = (size_t)blockIdx.z * M * N;
#pragma unroll
  for (int f = 0; f < 4; ++f)
#pragma unroll
    for (int g = 0; g < 8; ++g)
#pragma unroll
      for (int rr = 0; rr < 4; ++rr) {
        int row = bm + wm * 64 + f * 16 + l4 * 4 + rr;
        int col = bn + wn * 128 + g * 16 + l15;
        if (BF16_OUT)
          ((ushort*)Cv)[cz + (size_t)row * N + col] = f2b(acc[f][g][rr]);
        else
          ((float*)Cv)[cz + (size_t)row * N + col] = acc[f][g][rr];
      }
}

// ---------------- GEMM (2-phase, small shapes): C = A*B^T, bf16/f32 out ----------------
template<bool BF16_OUT>
__global__ __launch_bounds__(256, 2)
void gemm_bt(const ushort* __restrict__ A, int lda, const ushort* __restrict__ B, int ldb,
             void* __restrict__ Cv, int M, int N, int Kloop) {
  __shared__ ushort lA[128 * 64];
  __shared__ ushort lB[128 * 64];
  const int nwg = gridDim.x * gridDim.y;
  const int bid = blockIdx.y * gridDim.x + blockIdx.x;
  const int cpx = nwg >> 3;
  const int swz = (bid & 7) * cpx + (bid >> 3);
  const int bm = (swz / gridDim.x) * 128;
  const int bn = (swz % gridDim.x) * 128;
  const int t = threadIdx.x;
  const int lane = t & 63;
  const int w = t >> 6;
  const int wr = (w >> 1) * 64, wc = (w & 1) * 64;
  const int l15 = lane & 15, l4 = lane >> 4;

  f32x4 acc[4][4] = {};

  const ushort* Ag = A + (size_t)blockIdx.z * Kloop +
                     (size_t)(bm + w * 8 + (lane >> 3)) * lda + (lane & 7) * 8;
  const ushort* Bg = B + (size_t)blockIdx.z * Kloop +
                     (size_t)(bn + w * 8 + (lane >> 3)) * ldb + (lane & 7) * 8;
  ushort* lAw = lA + w * 8 * 64;
  ushort* lBw = lB + w * 8 * 64;

  for (int k0 = 0; k0 < Kloop; k0 += 64) {
    __syncthreads();
#pragma unroll
    for (int p = 0; p < 4; ++p) {
      load_lds16(Ag + (size_t)(p * 32) * lda + k0, lAw + p * 32 * 64);
      load_lds16(Bg + (size_t)(p * 32) * ldb + k0, lBw + p * 32 * 64);
    }
    __syncthreads();
#pragma unroll
    for (int kk = 0; kk < 2; ++kk) {
      s16x8 af[4], bf[4];
#pragma unroll
      for (int i = 0; i < 4; ++i)
        af[i] = *(const s16x8*)(lA + (wr + i * 16 + l15) * 64 + kk * 32 + l4 * 8);
#pragma unroll
      for (int j = 0; j < 4; ++j)
        bf[j] = *(const s16x8*)(lB + (wc + j * 16 + l15) * 64 + kk * 32 + l4 * 8);
#pragma unroll
      for (int i = 0; i < 4; ++i)
#pragma unroll
        for (int j = 0; j < 4; ++j)
          acc[i][j] = MFMA(af[i], bf[j], acc[i][j], 0, 0, 0);
    }
  }

  const size_t cz = (size_t)blockIdx.z * M * N;
#pragma unroll
  for (int i = 0; i < 4; ++i)
#pragma unroll
    for (int j = 0; j < 4; ++j)
#pragma unroll
      for (int r = 0; r < 4; ++r) {
        int row = bm + wr + i * 16 + l4 * 4 + r;
        int col = bn + wc + j * 16 + l15;
        if (BF16_OUT)
          ((ushort*)Cv)[cz + (size_t)row * N + col] = f2b(acc[i][j][r]);
        else
          ((float*)Cv)[cz + (size_t)row * N + col] = acc[i][j][r];
      }
}

// ---------------- fused causal GQA attention, QBLK=128, 8 waves ----------------
// Q is read as TWO bf16 split-K partials (qp_b layout) and reduced + rope'd
// in-register: fragment kk and kk+2 hold the rotate-half pair (d, d+64).
// setprio(1) around both MFMA clusters (T5: independent blocks at differing
// phases give the CU scheduler role diversity to arbitrate; m191 regime).
__global__ __launch_bounds__(512, 2)
void attn_kernel(const ushort* __restrict__ Qp, const float* __restrict__ cosb,
                 const float* __restrict__ sinb, const ushort* __restrict__ Kb,
                 const ushort* __restrict__ Vt, ushort* __restrict__ O) {
  __shared__ ushort Kl[2][64 * 128];
  __shared__ ushort Vl[2][128 * 64];
  __shared__ ushort Plds[8][16][64];
  const int bx = blockIdx.x;
  const int b = bx >> 8;
  const int qb = b ? (7 - (bx & 7)) : (bx & 7);
  const int h = (bx >> 3) & 31;
  const int kvh = h >> 2;
  const int w = threadIdx.x >> 6;
  const int lane = threadIdx.x & 63;
  const int l15 = lane & 15, l4 = lane >> 4;

  const int q0 = qb * 128 + w * 16;

  s16x8 aq[4];
  {
    const int bs_row = b * 1024 + q0 + l15;
    const ushort* prow0 = Qp + (size_t)bs_row * 4096 + h * 128 + l4 * 8;
    const ushort* prow1 = prow0 + 2048ull * 4096;
    float x[4][8];
#pragma unroll
    for (int kk = 0; kk < 4; ++kk) {
      s16x8 pa = *(const s16x8*)(prow0 + kk * 32);
      s16x8 pb = *(const s16x8*)(prow1 + kk * 32);
#pragma unroll
      for (int j = 0; j < 8; ++j) x[kk][j] = b2f((ushort)pa[j]) + b2f((ushort)pb[j]);
    }
    const float* cb = cosb + ((size_t)bs_row << 6);
    const float* sb = sinb + ((size_t)bs_row << 6);
#pragma unroll
    for (int kk = 0; kk < 2; ++kk)
#pragma unroll
      for (int j = 0; j < 8; ++j) {
        int dd = kk * 32 + l4 * 8 + j;
        float c = cb[dd], s = sb[dd];
        aq[kk][j]     = f2b(x[kk][j] * c - x[kk + 2][j] * s);
        aq[kk + 2][j] = f2b(x[kk + 2][j] * c + x[kk][j] * s);
      }
  }

  auto stageK = [&](int bb, int t) {
#pragma unroll
    for (int i = 0; i < 2; ++i) {
      int row0 = w * 8 + i * 4;
      int row = row0 + (lane >> 4);
      int cg = (lane & 15) ^ (row & 7);
      const ushort* src = Kb + (size_t)(b * 1024 + t * 64 + row) * 1024 + kvh * 128 + cg * 8;
      load_lds16(src, &Kl[bb][row0 * 128]);
    }
  };
  auto stageV = [&](int bb, int t) {
#pragma unroll
    for (int i = 0; i < 2; ++i) {
      int d0 = w * 16 + i * 8;
      int d = d0 + (lane >> 3);
      int cg = (lane & 7) ^ (d & 7);
      const ushort* src = Vt + (size_t)(kvh * 128 + d) * 2048 + b * 1024 + t * 64 + cg * 8;
      load_lds16(src, &Vl[bb][d0 * 64]);
    }
  };

  f32x4 o_acc[8] = {};
  float M_[4] = {-1e30f, -1e30f, -1e30f, -1e30f};
  float L_[4] = {0.f, 0.f, 0.f, 0.f};

  const int nt = 2 * qb + 2;
  int buf = 0;
  stageK(0, 0);
  stageV(0, 0);
  __syncthreads();

  for (int t = 0; t < nt; ++t) {
    if (t + 1 < nt) {
      stageK(buf ^ 1, t + 1);
      stageV(buf ^ 1, t + 1);
    }

    f32x4 s_acc[4] = {};
    __builtin_amdgcn_s_setprio(1);
#pragma unroll
    for (int ns = 0; ns < 4; ++ns) {
      int r = ns * 16 + l15;
#pragma unroll
      for (int kk = 0; kk < 4; ++kk) {
        s16x8 kf = *(const s16x8*)&Kl[buf][r * 128 + (((kk * 4 + l4) ^ (r & 7)) * 8)];
        s_acc[ns] = MFMA(aq[kk], kf, s_acc[ns], 0, 0, 0);
      }
    }
    __builtin_amdgcn_s_setprio(0);

    float p[4][4];
    const bool diag = (t * 64 + 63 > q0);
#pragma unroll
    for (int ns = 0; ns < 4; ++ns)
#pragma unroll
      for (int r = 0; r < 4; ++r) {
        float s = s_acc[ns][r] * 0.08838834764831845f;
        if (diag) {
          int kvi = t * 64 + ns * 16 + l15;
          int qi = q0 + l4 * 4 + r;
          if (kvi > qi) s = -1e30f;
        }
        p[ns][r] = s;
      }

#pragma unroll
    for (int r = 0; r < 4; ++r) {
      float mt = fmaxf(fmaxf(p[0][r], p[1][r]), fmaxf(p[2][r], p[3][r]));
      mt = fmaxf(mt, __shfl_xor(mt, 1));
      mt = fmaxf(mt, __shfl_xor(mt, 2));
      mt = fmaxf(mt, __shfl_xor(mt, 4));
      mt = fmaxf(mt, __shfl_xor(mt, 8));
      float nm = fmaxf(M_[r], mt);
      float sf = __expf(M_[r] - nm);
      M_[r] = nm;
      float ls = 0.f;
#pragma unroll
      for (int ns = 0; ns < 4; ++ns) {
        float e = __expf(p[ns][r] - nm);
        p[ns][r] = e;
        ls += e;
      }
      ls += __shfl_xor(ls, 1);
      ls += __shfl_xor(ls, 2);
      ls += __shfl_xor(ls, 4);
      ls += __shfl_xor(ls, 8);
      L_[r] = L_[r] * sf + ls;
#pragma unroll
      for (int ds_ = 0; ds_ < 8; ++ds_) o_acc[ds_][r] *= sf;
    }

#pragma unroll
    for (int ns = 0; ns < 4; ++ns)
#pragma unroll
      for (int r = 0; r < 4; ++r)
        Plds[w][l4 * 4 + r][ns * 16 + l15] = f2b(p[ns][r]);
    asm volatile("s_waitcnt lgkmcnt(0)" ::: "memory");
    __builtin_amdgcn_sched_barrier(0);
    s16x8 pf[2];
    pf[0] = *(const s16x8*)&Plds[w][l15][l4 * 8];
    pf[1] = *(const s16x8*)&Plds[w][l15][32 + l4 * 8];

    __builtin_amdgcn_s_setprio(1);
#pragma unroll
    for (int ds_ = 0; ds_ < 8; ++ds_) {
      int d = ds_ * 16 + l15;
#pragma unroll
      for (int kk2 = 0; kk2 < 2; ++kk2) {
        s16x8 vf = *(const s16x8*)&Vl[buf][d * 64 + (((kk2 * 4 + l4) ^ (d & 7)) * 8)];
        o_acc[ds_] = MFMA(pf[kk2], vf, o_acc[ds_], 0, 0, 0);
      }
    }
    __builtin_amdgcn_s_setprio(0);

    __syncthreads();
    buf ^= 1;
  }

#pragma unroll
  for (int r = 0; r < 4; ++r) {
    float invl = 1.0f / L_[r];
#pragma unroll
    for (int ds_ = 0; ds_ < 8; ++ds_)
      O[(size_t)(b * 1024 + q0 + l4 * 4 + r) * 4096 + h * 128 + ds_ * 16 + l15] =
          f2b(o_acc[ds_][r] * invl);
  }
}

// ---------------- host ----------------
extern "C" void kernel_launch(void* const* d_in, const int* in_sizes, int n_in,
                              void* d_out, int out_size, void* d_ws, size_t ws_size,
                              hipStream_t stream) {
  const float* hs = (const float*)d_in[0];
  const int* pos = (const int*)d_in[1];
  const float* Wq = (const float*)d_in[2];
  const float* Wdkv = (const float*)d_in[3];
  const float* gam = (const float*)d_in[4];
  const float* bet = (const float*)d_in[5];
  const float* Wuk = (const float*)d_in[6];
  const float* Wuv = (const float*)d_in[7];
  const float* Wo = (const float*)d_in[8];
  float* out = (float*)d_out;

  char* ws = (char*)d_ws;
  size_t off = 0;
  auto alloc = [&](size_t bytes) {
    char* p = ws + off;
    off += (bytes + 255) & ~(size_t)255;
    return p;
  };
  ushort* hs_b = (ushort*)alloc(2048ull * 8192 * 2);
  ushort* Wq_b = (ushort*)alloc(4096ull * 8192 * 2);
  ushort* Wdkv_b = (ushort*)alloc(256ull * 8192 * 2);
  ushort* Wuk_b = (ushort*)alloc(1024ull * 256 * 2);
  ushort* Wuv_b = (ushort*)alloc(1024ull * 256 * 2);
  ushort* Wo_b = (ushort*)alloc(4096ull * 4096 * 2);
  float* cosb = (float*)alloc(2048ull * 64 * 4);
  float* sinb = (float*)alloc(2048ull * 64 * 4);
  float* ckv_part = (float*)alloc(8ull * 2048 * 256 * 4);
  ushort* ckv_b = (ushort*)alloc(2048ull * 256 * 2);
  ushort* qp_b = (ushort*)alloc(2ull * 2048 * 4096 * 2);  // Q bf16 partials; reused for O partials
  ushort* k_b = (ushort*)alloc(2048ull * 1024 * 2);
  ushort* vt_b = (ushort*)alloc(1024ull * 2048 * 2);
  ushort* at_b = (ushort*)alloc(2048ull * 4096 * 2);
  (void)ws_size; (void)in_sizes; (void)n_in; (void)out_size;

  cast6_kernel<<<2048, 256, 0, stream>>>(
      hs, hs_b, (int)(2048ull * 8192 / 8),
      Wq, Wq_b, (int)(4096ull * 8192 / 8),
      Wdkv, Wdkv_b, (int)(256ull * 8192 / 8),
      Wuk, Wuk_b, (int)(1024ull * 256 / 8),
      Wuv, Wuv_b, (int)(1024ull * 256 / 8),
      Wo, Wo_b, (int)(4096ull * 4096 / 8),
      pos, cosb, sinb);

  // c_kv = LN(hs @ Wdkv^T), split-K=8 + fused reduction in ln_kernel
  gemm_bt<false><<<dim3(2, 16, 8), 256, 0, stream>>>(hs_b, 8192, Wdkv_b, 8192,
                                                     ckv_part, 2048, 256, 1024);
  ln_kernel<<<512, 256, 0, stream>>>(ckv_part, gam, bet, ckv_b);

  // q partials = hs @ Wq^T (split-K=2, bf16); reduce+rope happens inside attn
  gemm2_bt<true><<<dim3(16, 16, 2), 256, 0, stream>>>(hs_b, 8192, Wq_b, 8192,
                                                      qp_b, 2048, 4096, 4096);

  // k = rope(ckv @ Wuk^T), bf16 direct + in-place rope
  gemm_bt<true><<<dim3(8, 16), 256, 0, stream>>>(ckv_b, 256, Wuk_b, 256,
                                                 k_b, 2048, 1024, 256);
  rope_apply_bf16<8><<<2048, 256, 0, stream>>>(k_b, cosb, sinb);

  // v^T = Wuv @ ckv^T  (directly transposed: [1024, 2048] bf16)
  gemm_bt<true><<<dim3(16, 8), 256, 0, stream>>>(Wuv_b, 256, ckv_b, 256,
                                                 vt_b, 1024, 2048, 256);

  // attention (consumes Q partials directly): QBLK=128, 512 blocks, 512 threads
  attn_kernel<<<512, 512, 0, stream>>>(qp_b, cosb, sinb, k_b, vt_b, at_b);

  // out = attn @ Wo^T: split-K=2, bf16 partials into qp_b (free after attn)
  gemm2_bt<true><<<dim3(16, 16, 2), 256, 0, stream>>>(at_b, 4096, Wo_b, 4096,
                                                      qp_b, 2048, 4096, 2048);
  ored_kernel<<<2048, 256, 0, stream>>>(qp_b, out, (int)(2048ull * 4096 / 8));
}